// Round 23
// baseline (146.682 us; speedup 1.0000x reference)
//
#include <hip/hip_runtime.h>

#define KCLS 19
#define CCH 64
#define HW (512*512)
#define NPIX (4*HW)          // 1,048,576 pixels

#define CHUNK 8192           // pixels per block (32 chunks per image)
#define NCHUNK (NPIX/CHUNK)  // 128

// ws float offsets (stats area)
#define WS_COUNTS  0      // 19
#define WS_SUMS    32     // [k*64+c], 1216
#define WS_VARSUM  1280   // 19
#define WS_NFLOATS 2576
#define WS_CNTP    2624   // 256 x 19 per-block count partials (plain stores)
#define WS_U8_BYTE_OFF  65536                      // packed u8 labels, 1 MB
#define WS_FP8_BYTE_OFF (65536 + 1048576)          // fp8 copy of pred (plane layout), 64 MB

typedef float f32x2 __attribute__((ext_vector_type(2)));

__device__ __forceinline__ void ldsAdd(float* p, float v) { unsafeAtomicAdd(p, v); }

// ---------------- K0: zero stats + pack labels + per-block count partials ----------------
// 256 blocks x 256 thr; thread j packs 16 labels; per-thread LDS rows for counts.
__global__ __launch_bounds__(256) void k0_prep(const int* __restrict__ tgt,
                                               float* __restrict__ ws,
                                               unsigned* __restrict__ u8buf) {
    const int t = threadIdx.x;
    const int l = t & 63;
    const int w = t >> 6;
    const int j = blockIdx.x * 256 + t;

    __shared__ float bins[256 * 21];
    __shared__ float red[4 * 21];

    float* br = &bins[t * 21];
    #pragma unroll
    for (int k = 0; k < KCLS; ++k) br[k] = 0.0f;
    if (blockIdx.x == 0) {
        for (int i = t; i < WS_NFLOATS; i += 256) ws[i] = 0.0f;
    }

    const int4* tg4 = (const int4*)tgt;
    unsigned pk[4];
    #pragma unroll
    for (int q = 0; q < 4; ++q) {
        int4 L = tg4[j * 4 + q];
        pk[q] = (unsigned)(L.x & 0xFF) | ((unsigned)(L.y & 0xFF) << 8) |
                ((unsigned)(L.z & 0xFF) << 16) | ((unsigned)(L.w & 0xFF) << 24);
        br[L.x & 31] += 1.0f;
        br[L.y & 31] += 1.0f;
        br[L.z & 31] += 1.0f;
        br[L.w & 31] += 1.0f;
    }
    uint4 o; o.x = pk[0]; o.y = pk[1]; o.z = pk[2]; o.w = pk[3];
    ((uint4*)u8buf)[j] = o;

    __syncthreads();
    if (l < KCLS) {
        float s = 0.0f;
        const int rbase = w * 64;
        #pragma unroll 8
        for (int r = 0; r < 64; ++r) s += bins[(rbase + r) * 21 + l];
        red[w * 21 + l] = s;
    }
    __syncthreads();
    if (t < KCLS) {
        float s = red[t] + red[21 + t] + red[42 + t] + red[63 + t];
        ws[WS_CNTP + blockIdx.x * 19 + t] = s;
    }
}

// ---------------- K1: one channel per block; zero mid-kernel barriers ----------------
// grid (128 chunks, 64 channels), block 256 (4 waves). Each thread: 8 float4 iters.
// Halved CHUNK vs R22: per-thread LDS RMW alias-chain halves; 2x blocks overlap.
__global__ __launch_bounds__(256) void k1_sums(const float* __restrict__ pred,
                                               const unsigned* __restrict__ u8buf,
                                               float* __restrict__ ws,
                                               unsigned* __restrict__ fp8buf) {
    const int t = threadIdx.x;
    const int l = t & 63;
    const int w = t >> 6;
    const int chunk = blockIdx.x;        // 128
    const int c = blockIdx.y;            // 64
    const int n = chunk >> 5;            // 32 chunks per image
    const int choff = (chunk & 31) * CHUNK;

    __shared__ float bins[256 * 21];     // thread-private rows
    __shared__ float red[4 * 21];

    float* br = &bins[t * 21];
    #pragma unroll
    for (int k = 0; k < KCLS; ++k) br[k] = 0.0f;

    // c==0 blocks fold count partials into WS_COUNTS (2 k0-partials per chunk)
    if (c == 0 && t < 38) {
        float v = ws[WS_CNTP + (chunk * 2 + t / 19) * 19 + (t % 19)];
        unsafeAtomicAdd(&ws[WS_COUNTS + (t % 19)], v);
    }

    const size_t plane = (size_t)(n * CCH + c) * HW + choff;
    const float4* src = (const float4*)(pred + plane) + w * 512;
    unsigned* dst8 = fp8buf + (plane >> 2) + w * 512;
    const unsigned* lwp = u8buf + chunk * 2048 + w * 512;

    unsigned pkbuf[8];

    #pragma unroll 1
    for (int b = 0; b < 2; ++b) {
        float4 cv[4]; unsigned cl[4];
        #pragma unroll
        for (int j = 0; j < 4; ++j) {
            cv[j] = src[(b * 4 + j) * 64 + l];
            cl[j] = lwp[(b * 4 + j) * 64 + l];
        }
        #pragma unroll
        for (int j = 0; j < 4; ++j) {
            const unsigned lw = cl[j];
            const float4 v = cv[j];
            br[lw & 31] += v.x;
            br[(lw >> 8) & 31] += v.y;
            br[(lw >> 16) & 31] += v.z;
            br[(lw >> 24) & 31] += v.w;
            int pk = 0;
            pk = __builtin_amdgcn_cvt_pk_fp8_f32(v.x, v.y, pk, false);
            pk = __builtin_amdgcn_cvt_pk_fp8_f32(v.z, v.w, pk, true);
            pkbuf[b * 4 + j] = (unsigned)pk;
        }
    }

    // NT store burst (drained only at the single flush barrier)
    #pragma unroll
    for (int i = 0; i < 8; ++i)
        __builtin_nontemporal_store(pkbuf[i], &dst8[i * 64 + l]);

    // single flush
    __syncthreads();
    if (l < KCLS) {
        float s = 0.0f;
        const int rbase = w * 64;
        #pragma unroll 8
        for (int r = 0; r < 64; ++r) s += bins[(rbase + r) * 21 + l];
        red[w * 21 + l] = s;
    }
    __syncthreads();
    if (t < KCLS) {
        float s = red[t] + red[21 + t] + red[42 + t] + red[63 + t];
        unsafeAtomicAdd(&ws[WS_SUMS + t * CCH + c], s);
    }
}

// ---------------- K3: pull term from fp8 plane copy; 8-deep channel prefetch ----------------
// grid: 1024 chunks of 1024 pixels, block 256 (4 px/thread), reversed order.
__global__ __launch_bounds__(256) void k3_var(const unsigned* __restrict__ fp8buf,
                                              const int* __restrict__ tgt,
                                              float* __restrict__ ws) {
    const int t = threadIdx.x;
    const int cid = 1023 - blockIdx.x;
    const int n = cid >> 8;
    const int hwb = (cid & 255) * 1024;

    __shared__ float ct[CCH * 20];       // ct[c*20 + k]
    __shared__ float cntS[KCLS];
    __shared__ float varh[80];

    if (t < KCLS) cntS[t] = ws[WS_COUNTS + t];
    if (t < 80) varh[t] = 0.0f;
    __syncthreads();
    for (int i = t; i < CCH * 20; i += 256) {
        int c = i / 20, k = i % 20;
        ct[i] = (k < KCLS) ? ws[WS_SUMS + k * CCH + c] / fmaxf(cntS[k], 1.0f) : 0.0f;
    }

    const int4 l0 = ((const int4*)(tgt + n * HW + hwb))[t];
    const int lab0 = l0.x, lab1 = l0.y, lab2 = l0.z, lab3 = l0.w;
    float a0 = 0.0f, a1 = 0.0f, a2 = 0.0f, a3 = 0.0f;
    __syncthreads();

    const unsigned* base8 = fp8buf + (((size_t)n * CCH * HW + hwb) >> 2);

    unsigned wb[8], nb[8];
    #pragma unroll
    for (int j = 0; j < 8; ++j) wb[j] = base8[j * (HW / 4) + t];

    #pragma unroll 1
    for (int cb = 0; cb < 8; ++cb) {
        if (cb < 7) {
            #pragma unroll
            for (int j = 0; j < 8; ++j) nb[j] = base8[((cb + 1) * 8 + j) * (HW / 4) + t];
        }
        const int cbase = cb * 8;
        #pragma unroll
        for (int j = 0; j < 8; ++j) {
            const unsigned w8 = wb[j];
            f32x2 lo = __builtin_amdgcn_cvt_pk_f32_fp8(w8, false);
            f32x2 hi = __builtin_amdgcn_cvt_pk_f32_fp8(w8, true);
            const float* row = &ct[(cbase + j) * 20];
            float m0 = row[lab0], m1 = row[lab1], m2 = row[lab2], m3 = row[lab3];
            float d0 = lo.x - m0, d1 = lo.y - m1, d2 = hi.x - m2, d3 = hi.y - m3;
            a0 = fmaf(d0, d0, a0);
            a1 = fmaf(d1, d1, a1);
            a2 = fmaf(d2, d2, a2);
            a3 = fmaf(d3, d3, a3);
        }
        #pragma unroll
        for (int j = 0; j < 8; ++j) wb[j] = nb[j];
    }

    const int rep = (t & 3) * KCLS;
    {
        float d, r;
        d = sqrtf(fmaxf(a0, 1e-12f)); r = d - 0.5f; if (r > 0.0f) ldsAdd(&varh[rep + lab0], r * r);
        d = sqrtf(fmaxf(a1, 1e-12f)); r = d - 0.5f; if (r > 0.0f) ldsAdd(&varh[rep + lab1], r * r);
        d = sqrtf(fmaxf(a2, 1e-12f)); r = d - 0.5f; if (r > 0.0f) ldsAdd(&varh[rep + lab2], r * r);
        d = sqrtf(fmaxf(a3, 1e-12f)); r = d - 0.5f; if (r > 0.0f) ldsAdd(&varh[rep + lab3], r * r);
    }
    __syncthreads();
    if (t < KCLS) {
        float s = varh[t] + varh[19 + t] + varh[38 + t] + varh[57 + t];
        unsafeAtomicAdd(&ws[WS_VARSUM + t], s);
    }
}

// ---------------- K4: centers + push + reg + final combine (1 block) ----------------
__global__ __launch_bounds__(256) void k4_final(const float* __restrict__ ws,
                                                float* __restrict__ out) {
    __shared__ float ct[CCH * 20];
    __shared__ float cntS[KCLS];
    __shared__ float acc[2];
    const int t = threadIdx.x;
    if (t < KCLS) cntS[t] = ws[WS_COUNTS + t];
    if (t < 2) acc[t] = 0.0f;
    __syncthreads();
    for (int i = t; i < CCH * 20; i += 256) {
        int c = i / 20, k = i % 20;
        ct[i] = (k < KCLS) ? ws[WS_SUMS + k * CCH + c] / fmaxf(cntS[k], 1.0f) : 0.0f;
    }
    __syncthreads();

    for (int p = t; p < KCLS * KCLS; p += 256) {
        int i = p / KCLS, j = p % KCLS;
        if (i != j && cntS[i] > 20.0f && cntS[j] > 20.0f) {
            float sq = 0.0f;
            #pragma unroll 8
            for (int c = 0; c < CCH; ++c) {
                float d = ct[c * 20 + i] - ct[c * 20 + j];
                sq = fmaf(d, d, sq);
            }
            float pd = sqrtf(sq);
            float r = 3.0f - pd;        // 2*DELTA - pd
            if (r > 0.0f) atomicAdd(&acc[0], r * r);
        }
    }
    if (t < KCLS && cntS[t] > 20.0f) {
        float sq = 0.0f;
        #pragma unroll 8
        for (int c = 0; c < CCH; ++c) { float v = ct[c * 20 + t]; sq = fmaf(v, v, sq); }
        atomicAdd(&acc[1], sqrtf(sq));
    }
    __syncthreads();

    if (t < 64) {
        float v = 0.0f;
        if (t < KCLS) {
            float c = cntS[t];
            if (c > 20.0f) v = ws[WS_VARSUM + t] / fmaxf(c, 1.0f);
        }
        #pragma unroll
        for (int s = 32; s > 0; s >>= 1) v += __shfl_down(v, s);
        if (t == 0) {
            float nv = 0.0f;
            for (int k = 0; k < KCLS; ++k) nv += (cntS[k] > 20.0f) ? 1.0f : 0.0f;
            float loss_dis = acc[0] / fmaxf(nv * (nv - 1.0f), 1.0f);
            float loss_reg = acc[1] / fmaxf(nv, 1.0f);
            out[0] = v / fmaxf(nv, 1.0f) + loss_dis + 0.001f * loss_reg;
        }
    }
}

extern "C" void kernel_launch(void* const* d_in, const int* in_sizes, int n_in,
                              void* d_out, int out_size, void* d_ws, size_t ws_size,
                              hipStream_t stream) {
    const float* pred = (const float*)d_in[0];
    const int* tgt = (const int*)d_in[1];
    float* ws = (float*)d_ws;
    unsigned* u8buf = (unsigned*)((char*)d_ws + WS_U8_BYTE_OFF);
    unsigned* fp8buf = (unsigned*)((char*)d_ws + WS_FP8_BYTE_OFF);
    float* out = (float*)d_out;

    hipLaunchKernelGGL(k0_prep, dim3(256), dim3(256), 0, stream, tgt, ws, u8buf);
    hipLaunchKernelGGL(k1_sums, dim3(NCHUNK, CCH), dim3(256), 0, stream, pred, u8buf, ws, fp8buf);
    hipLaunchKernelGGL(k3_var, dim3(1024), dim3(256), 0, stream, fp8buf, tgt, ws);
    hipLaunchKernelGGL(k4_final, dim3(1), dim3(256), 0, stream, ws, out);
}

// Round 24
// 112.178 us; speedup vs baseline: 1.3076x; 1.3076x over previous
//
#include <hip/hip_runtime.h>

#define KCLS 19
#define CCH 64
#define HW (512*512)
#define NPIX (4*HW)          // 1,048,576 pixels

#define CHUNK 32768          // pixels per block (8 chunks per image)
#define NCHUNK (NPIX/CHUNK)  // 32

// ws float offsets (stats area)
#define WS_COUNTS  0      // 19
#define WS_SUMS    32     // [k*64+c], 1216
#define WS_VARSUM  1280   // 19
#define WS_NFLOATS 2576
#define WS_CNTP    2624   // 256 x 19 per-block count partials (plain stores)
#define WS_U8_BYTE_OFF  65536                      // packed u8 labels, 1 MB
#define WS_FP8_BYTE_OFF (65536 + 1048576)          // fp8 copy of pred (plane layout), 64 MB

typedef float f32x2 __attribute__((ext_vector_type(2)));

__device__ __forceinline__ void ldsAdd(float* p, float v) { unsafeAtomicAdd(p, v); }

// ---------------- K0: zero stats + pack labels + per-block count partials ----------------
__global__ __launch_bounds__(256) void k0_prep(const int* __restrict__ tgt,
                                               float* __restrict__ ws,
                                               unsigned* __restrict__ u8buf) {
    const int t = threadIdx.x;
    const int l = t & 63;
    const int w = t >> 6;
    const int j = blockIdx.x * 256 + t;

    __shared__ float bins[256 * 21];
    __shared__ float red[4 * 21];

    float* br = &bins[t * 21];
    #pragma unroll
    for (int k = 0; k < KCLS; ++k) br[k] = 0.0f;
    if (blockIdx.x == 0) {
        for (int i = t; i < WS_NFLOATS; i += 256) ws[i] = 0.0f;
    }

    const int4* tg4 = (const int4*)tgt;
    unsigned pk[4];
    #pragma unroll
    for (int q = 0; q < 4; ++q) {
        int4 L = tg4[j * 4 + q];
        pk[q] = (unsigned)(L.x & 0xFF) | ((unsigned)(L.y & 0xFF) << 8) |
                ((unsigned)(L.z & 0xFF) << 16) | ((unsigned)(L.w & 0xFF) << 24);
        br[L.x & 31] += 1.0f;
        br[L.y & 31] += 1.0f;
        br[L.z & 31] += 1.0f;
        br[L.w & 31] += 1.0f;
    }
    uint4 o; o.x = pk[0]; o.y = pk[1]; o.z = pk[2]; o.w = pk[3];
    ((uint4*)u8buf)[j] = o;

    __syncthreads();
    if (l < KCLS) {
        float s = 0.0f;
        const int rbase = w * 64;
        #pragma unroll 8
        for (int r = 0; r < 64; ++r) s += bins[(rbase + r) * 21 + l];
        red[w * 21 + l] = s;
    }
    __syncthreads();
    if (t < KCLS) {
        float s = red[t] + red[21 + t] + red[42 + t] + red[63 + t];
        ws[WS_CNTP + blockIdx.x * 19 + t] = s;
    }
}

// ---------------- K1: one channel per block, CHUNK=32K; zero mid-kernel barriers ----------------
// grid (32 chunks, 64 channels), block 256 (4 waves). Each thread: 32 float4 iters
// in two 16-iter halves (pkbuf[16] per half). Single flush barrier at end.
__global__ __launch_bounds__(256) void k1_sums(const float* __restrict__ pred,
                                               const unsigned* __restrict__ u8buf,
                                               float* __restrict__ ws,
                                               unsigned* __restrict__ fp8buf) {
    const int t = threadIdx.x;
    const int l = t & 63;
    const int w = t >> 6;
    const int chunk = blockIdx.x;        // 32
    const int c = blockIdx.y;            // 64
    const int n = chunk >> 3;            // 8 chunks per image
    const int choff = (chunk & 7) * CHUNK;

    __shared__ float bins[256 * 21];     // thread-private rows
    __shared__ float red[4 * 21];

    float* br = &bins[t * 21];
    #pragma unroll
    for (int k = 0; k < KCLS; ++k) br[k] = 0.0f;

    // c==0 blocks fold count partials into WS_COUNTS (8 k0-partials per chunk)
    if (c == 0 && t < 152) {
        float v = ws[WS_CNTP + (chunk * 8 + t / 19) * 19 + (t % 19)];
        unsafeAtomicAdd(&ws[WS_COUNTS + (t % 19)], v);
    }

    const size_t plane = (size_t)(n * CCH + c) * HW + choff;
    const float4* src = (const float4*)(pred + plane) + w * 2048;
    unsigned* dst8 = fp8buf + (plane >> 2) + w * 2048;
    const unsigned* lwp = u8buf + chunk * (CHUNK / 4) + w * 2048;

    #pragma unroll 1
    for (int h = 0; h < 2; ++h) {
        unsigned pkbuf[16];
        #pragma unroll 1
        for (int b = 0; b < 4; ++b) {
            const int g = h * 16 + b * 4;
            float4 cv[4]; unsigned cl[4];
            #pragma unroll
            for (int j = 0; j < 4; ++j) {
                cv[j] = src[(g + j) * 64 + l];
                cl[j] = lwp[(g + j) * 64 + l];
            }
            #pragma unroll
            for (int j = 0; j < 4; ++j) {
                const unsigned lw = cl[j];
                const float4 v = cv[j];
                br[lw & 31] += v.x;
                br[(lw >> 8) & 31] += v.y;
                br[(lw >> 16) & 31] += v.z;
                br[(lw >> 24) & 31] += v.w;
                int pk = 0;
                pk = __builtin_amdgcn_cvt_pk_fp8_f32(v.x, v.y, pk, false);
                pk = __builtin_amdgcn_cvt_pk_fp8_f32(v.z, v.w, pk, true);
                pkbuf[b * 4 + j] = (unsigned)pk;
            }
        }
        // NT store burst for this half (no barrier -> no drain)
        #pragma unroll
        for (int i = 0; i < 16; ++i)
            __builtin_nontemporal_store(pkbuf[i], &dst8[(h * 16 + i) * 64 + l]);
    }

    // single flush
    __syncthreads();
    if (l < KCLS) {
        float s = 0.0f;
        const int rbase = w * 64;
        #pragma unroll 8
        for (int r = 0; r < 64; ++r) s += bins[(rbase + r) * 21 + l];
        red[w * 21 + l] = s;
    }
    __syncthreads();
    if (t < KCLS) {
        float s = red[t] + red[21 + t] + red[42 + t] + red[63 + t];
        unsafeAtomicAdd(&ws[WS_SUMS + t * CCH + c], s);
    }
}

// ---------------- K3: pull term from fp8 plane copy; 8-deep channel prefetch ----------------
__global__ __launch_bounds__(256) void k3_var(const unsigned* __restrict__ fp8buf,
                                              const int* __restrict__ tgt,
                                              float* __restrict__ ws) {
    const int t = threadIdx.x;
    const int cid = 1023 - blockIdx.x;
    const int n = cid >> 8;
    const int hwb = (cid & 255) * 1024;

    __shared__ float ct[CCH * 20];       // ct[c*20 + k]
    __shared__ float cntS[KCLS];
    __shared__ float varh[80];

    if (t < KCLS) cntS[t] = ws[WS_COUNTS + t];
    if (t < 80) varh[t] = 0.0f;
    __syncthreads();
    for (int i = t; i < CCH * 20; i += 256) {
        int c = i / 20, k = i % 20;
        ct[i] = (k < KCLS) ? ws[WS_SUMS + k * CCH + c] / fmaxf(cntS[k], 1.0f) : 0.0f;
    }

    const int4 l0 = ((const int4*)(tgt + n * HW + hwb))[t];
    const int lab0 = l0.x, lab1 = l0.y, lab2 = l0.z, lab3 = l0.w;
    float a0 = 0.0f, a1 = 0.0f, a2 = 0.0f, a3 = 0.0f;
    __syncthreads();

    const unsigned* base8 = fp8buf + (((size_t)n * CCH * HW + hwb) >> 2);

    unsigned wb[8], nb[8];
    #pragma unroll
    for (int j = 0; j < 8; ++j) wb[j] = base8[j * (HW / 4) + t];

    #pragma unroll 1
    for (int cb = 0; cb < 8; ++cb) {
        if (cb < 7) {
            #pragma unroll
            for (int j = 0; j < 8; ++j) nb[j] = base8[((cb + 1) * 8 + j) * (HW / 4) + t];
        }
        const int cbase = cb * 8;
        #pragma unroll
        for (int j = 0; j < 8; ++j) {
            const unsigned w8 = wb[j];
            f32x2 lo = __builtin_amdgcn_cvt_pk_f32_fp8(w8, false);
            f32x2 hi = __builtin_amdgcn_cvt_pk_f32_fp8(w8, true);
            const float* row = &ct[(cbase + j) * 20];
            float m0 = row[lab0], m1 = row[lab1], m2 = row[lab2], m3 = row[lab3];
            float d0 = lo.x - m0, d1 = lo.y - m1, d2 = hi.x - m2, d3 = hi.y - m3;
            a0 = fmaf(d0, d0, a0);
            a1 = fmaf(d1, d1, a1);
            a2 = fmaf(d2, d2, a2);
            a3 = fmaf(d3, d3, a3);
        }
        #pragma unroll
        for (int j = 0; j < 8; ++j) wb[j] = nb[j];
    }

    const int rep = (t & 3) * KCLS;
    {
        float d, r;
        d = sqrtf(fmaxf(a0, 1e-12f)); r = d - 0.5f; if (r > 0.0f) ldsAdd(&varh[rep + lab0], r * r);
        d = sqrtf(fmaxf(a1, 1e-12f)); r = d - 0.5f; if (r > 0.0f) ldsAdd(&varh[rep + lab1], r * r);
        d = sqrtf(fmaxf(a2, 1e-12f)); r = d - 0.5f; if (r > 0.0f) ldsAdd(&varh[rep + lab2], r * r);
        d = sqrtf(fmaxf(a3, 1e-12f)); r = d - 0.5f; if (r > 0.0f) ldsAdd(&varh[rep + lab3], r * r);
    }
    __syncthreads();
    if (t < KCLS) {
        float s = varh[t] + varh[19 + t] + varh[38 + t] + varh[57 + t];
        unsafeAtomicAdd(&ws[WS_VARSUM + t], s);
    }
}

// ---------------- K4: centers + push + reg + final combine (1 block) ----------------
__global__ __launch_bounds__(256) void k4_final(const float* __restrict__ ws,
                                                float* __restrict__ out) {
    __shared__ float ct[CCH * 20];
    __shared__ float cntS[KCLS];
    __shared__ float acc[2];
    const int t = threadIdx.x;
    if (t < KCLS) cntS[t] = ws[WS_COUNTS + t];
    if (t < 2) acc[t] = 0.0f;
    __syncthreads();
    for (int i = t; i < CCH * 20; i += 256) {
        int c = i / 20, k = i % 20;
        ct[i] = (k < KCLS) ? ws[WS_SUMS + k * CCH + c] / fmaxf(cntS[k], 1.0f) : 0.0f;
    }
    __syncthreads();

    for (int p = t; p < KCLS * KCLS; p += 256) {
        int i = p / KCLS, j = p % KCLS;
        if (i != j && cntS[i] > 20.0f && cntS[j] > 20.0f) {
            float sq = 0.0f;
            #pragma unroll 8
            for (int c = 0; c < CCH; ++c) {
                float d = ct[c * 20 + i] - ct[c * 20 + j];
                sq = fmaf(d, d, sq);
            }
            float pd = sqrtf(sq);
            float r = 3.0f - pd;        // 2*DELTA - pd
            if (r > 0.0f) atomicAdd(&acc[0], r * r);
        }
    }
    if (t < KCLS && cntS[t] > 20.0f) {
        float sq = 0.0f;
        #pragma unroll 8
        for (int c = 0; c < CCH; ++c) { float v = ct[c * 20 + t]; sq = fmaf(v, v, sq); }
        atomicAdd(&acc[1], sqrtf(sq));
    }
    __syncthreads();

    if (t < 64) {
        float v = 0.0f;
        if (t < KCLS) {
            float c = cntS[t];
            if (c > 20.0f) v = ws[WS_VARSUM + t] / fmaxf(c, 1.0f);
        }
        #pragma unroll
        for (int s = 32; s > 0; s >>= 1) v += __shfl_down(v, s);
        if (t == 0) {
            float nv = 0.0f;
            for (int k = 0; k < KCLS; ++k) nv += (cntS[k] > 20.0f) ? 1.0f : 0.0f;
            float loss_dis = acc[0] / fmaxf(nv * (nv - 1.0f), 1.0f);
            float loss_reg = acc[1] / fmaxf(nv, 1.0f);
            out[0] = v / fmaxf(nv, 1.0f) + loss_dis + 0.001f * loss_reg;
        }
    }
}

extern "C" void kernel_launch(void* const* d_in, const int* in_sizes, int n_in,
                              void* d_out, int out_size, void* d_ws, size_t ws_size,
                              hipStream_t stream) {
    const float* pred = (const float*)d_in[0];
    const int* tgt = (const int*)d_in[1];
    float* ws = (float*)d_ws;
    unsigned* u8buf = (unsigned*)((char*)d_ws + WS_U8_BYTE_OFF);
    unsigned* fp8buf = (unsigned*)((char*)d_ws + WS_FP8_BYTE_OFF);
    float* out = (float*)d_out;

    hipLaunchKernelGGL(k0_prep, dim3(256), dim3(256), 0, stream, tgt, ws, u8buf);
    hipLaunchKernelGGL(k1_sums, dim3(NCHUNK, CCH), dim3(256), 0, stream, pred, u8buf, ws, fp8buf);
    hipLaunchKernelGGL(k3_var, dim3(1024), dim3(256), 0, stream, fp8buf, tgt, ws);
    hipLaunchKernelGGL(k4_final, dim3(1), dim3(256), 0, stream, ws, out);
}